// Round 1
// 467.666 us; speedup vs baseline: 1.0114x; 1.0114x over previous
//
#include <hip/hip_runtime.h>
#include <stdint.h>
#include <stddef.h>

// GAT layer, N=8192, Fin=512, F=256 on gfx950.
// R8 = R7 + k_attn B-operand LDS double-buffer staging via global_load_lds
// (width 16), issued one phase ahead so L2 latency hides under the previous
// phase's MFMA + P-gen; removes the rg-duplicated global HTf reads.
// + s_setprio(1) around the MFMA cluster (T5).
// R7: k_attn with no cross-barrier register staging, P via LDS dbuf,
// 1 barrier per 32-j phase, 128x256 blocks, acc 4x4/wave. adj -> u64 ballot
// mask M3[iblk][jw][row]. k_pre fuses gemm blocks (first) + mask blocks.

#define N_NODES 8192
#define FIN     512
#define FOUT    256
#define LRALPHA 0.2f
#define MI_SHIFT 16.0f   // >= max s2 (sigma~1.3); exact-math upper bound

typedef float f32x4 __attribute__((ext_vector_type(4)));
typedef short s16x8 __attribute__((ext_vector_type(8)));
typedef unsigned short u16x4 __attribute__((ext_vector_type(4)));
typedef int   i32x4 __attribute__((ext_vector_type(4)));
typedef unsigned long long u64;

typedef const uint32_t __attribute__((address_space(1)))* gas1_u32;
typedef uint32_t __attribute__((address_space(3)))* las3_u32;

__device__ __forceinline__ short f2bf_rne(float f) {
  uint32_t u = __builtin_bit_cast(uint32_t, f);
  u += 0x7fffu + ((u >> 16) & 1u);
  return (short)(u >> 16);
}
__device__ __forceinline__ short f2bf_fast(float f) {   // round-half-up
  uint32_t u = __builtin_bit_cast(uint32_t, f);
  return (short)((u + 0x8000u) >> 16);
}
__device__ __forceinline__ float bf2f(short s) {
  uint32_t u = ((uint32_t)(uint16_t)s) << 16;
  return __builtin_bit_cast(float, u);
}

// ---------------------------------------------------------------------------
// K0: WThi/WTlo[256][512] bf16 hi/lo split of W (transposed).
// ---------------------------------------------------------------------------
__global__ __launch_bounds__(256) void k_prep(const float* __restrict__ W,
                                              uint16_t* __restrict__ WThi,
                                              uint16_t* __restrict__ WTlo) {
  const int idx = blockIdx.x * 256 + threadIdx.x;
  const int n = idx >> 9;
  const int k = idx & 511;
  float v = W[k * FOUT + n];
  short h = f2bf_rne(v);
  WThi[idx] = (uint16_t)h;
  WTlo[idx] = (uint16_t)f2bf_rne(v - bf2f(h));
}

// ---------------------------------------------------------------------------
// K1 fused kernel: blocks [0,512) = GEMM (H=X@W + s1/s2 + HTf store),
//                  blocks [512, 2560) = adj -> ballot bitmask M3.
// M3 layout: u64 at [iblk=row/128][jw=j/64][r=row%128]; bit (j&63) = edge.
// ---------------------------------------------------------------------------
__global__ __launch_bounds__(256, 4) void k_pre(const float* __restrict__ X,
                                                const uint16_t* __restrict__ WThi,
                                                const uint16_t* __restrict__ WTlo,
                                                const float* __restrict__ a,
                                                const int* __restrict__ adj,
                                                uint16_t* __restrict__ HTf,
                                                float* __restrict__ s1g,
                                                float* __restrict__ s2g,
                                                u64* __restrict__ M3) {
  __shared__ float ls1[16], ls2[16];
  __shared__ uint16_t tile[FOUT * 16];   // [col][row_local]
  const int lane = threadIdx.x & 63;
  const int w    = threadIdx.x >> 6;

  if (blockIdx.x >= 512) {
    // ---- mask branch ----
    const int bxm  = blockIdx.x - 512;
    const int iblk = bxm >> 5;
    const int jc   = bxm & 31;
    const int L    = lane;
    const int* base = adj + (size_t)(iblk * 128 + w * 32) * N_NODES + jc * 256 + L;
    u64 keep0 = 0, keep1 = 0, keep2 = 0, keep3 = 0;
#pragma unroll
    for (int it = 0; it < 32; ++it) {
      const int* rp = base + (size_t)it * N_NODES;
      int v0 = rp[0], v1 = rp[64], v2 = rp[128], v3 = rp[192];
      u64 b0 = __ballot(v0 != 0);
      u64 b1 = __ballot(v1 != 0);
      u64 b2 = __ballot(v2 != 0);
      u64 b3 = __ballot(v3 != 0);
      if (L == it) { keep0 = b0; keep1 = b1; keep2 = b2; keep3 = b3; }
    }
    if (L < 32) {   // only the 32 row-owning lanes store
      const size_t mb = (size_t)iblk * 128 * 128 + (w * 32 + L);
      M3[mb + (size_t)(jc * 4 + 0) * 128] = keep0;
      M3[mb + (size_t)(jc * 4 + 1) * 128] = keep1;
      M3[mb + (size_t)(jc * 4 + 2) * 128] = keep2;
      M3[mb + (size_t)(jc * 4 + 3) * 128] = keep3;
    }
    return;
  }

  // ---- gemm branch ----
  const int m    = lane & 15;
  const int quad = lane >> 4;
  const int i0   = blockIdx.x * 16;
  const int colg = w * 64;

  f32x4 acc[4];
#pragma unroll
  for (int cb = 0; cb < 4; ++cb) { f32x4 z = {0.f,0.f,0.f,0.f}; acc[cb] = z; }

  for (int kt = 0; kt < FIN / 32; ++kt) {
    const int k0 = kt * 32 + quad * 8;
    const float* ap = X + (size_t)(i0 + m) * FIN + k0;
    f32x4 a0 = *(const f32x4*)ap;
    f32x4 a1 = *(const f32x4*)(ap + 4);
    s16x8 ahi, alo;
#pragma unroll
    for (int e = 0; e < 4; ++e) {
      short h0 = f2bf_rne(a0[e]); ahi[e] = h0; alo[e] = f2bf_rne(a0[e] - bf2f(h0));
      short h1 = f2bf_rne(a1[e]); ahi[4+e] = h1; alo[4+e] = f2bf_rne(a1[e] - bf2f(h1));
    }
#pragma unroll
    for (int cb = 0; cb < 4; ++cb) {
      const int n = colg + cb * 16 + m;
      s16x8 bhi = *(const s16x8*)(WThi + (size_t)n * FIN + k0);
      s16x8 blo = *(const s16x8*)(WTlo + (size_t)n * FIN + k0);
      acc[cb] = __builtin_amdgcn_mfma_f32_16x16x32_bf16(ahi, bhi, acc[cb], 0, 0, 0);
      acc[cb] = __builtin_amdgcn_mfma_f32_16x16x32_bf16(ahi, blo, acc[cb], 0, 0, 0);
      acc[cb] = __builtin_amdgcn_mfma_f32_16x16x32_bf16(alo, bhi, acc[cb], 0, 0, 0);
    }
  }

  float p1[4] = {0.f,0.f,0.f,0.f}, p2[4] = {0.f,0.f,0.f,0.f};
#pragma unroll
  for (int cb = 0; cb < 4; ++cb) {
    const int n = colg + cb * 16 + m;
    const float a1c = a[n];
    const float a2c = a[FOUT + n];
#pragma unroll
    for (int reg = 0; reg < 4; ++reg) {
      p1[reg] += acc[cb][reg] * a1c;
      p2[reg] += acc[cb][reg] * a2c;
    }
  }
#pragma unroll
  for (int off = 1; off <= 8; off <<= 1)
#pragma unroll
    for (int reg = 0; reg < 4; ++reg) {
      p1[reg] += __shfl_xor(p1[reg], off);
      p2[reg] += __shfl_xor(p2[reg], off);
    }
  if (threadIdx.x < 16) { ls1[threadIdx.x] = 0.f; ls2[threadIdx.x] = 0.f; }
  __syncthreads();
  if (m == 0) {
#pragma unroll
    for (int reg = 0; reg < 4; ++reg) {
      atomicAdd(&ls1[quad * 4 + reg], p1[reg]);
      atomicAdd(&ls2[quad * 4 + reg], p2[reg]);
    }
  }
#pragma unroll
  for (int cb = 0; cb < 4; ++cb) {
    const int col = colg + cb * 16 + m;
    u16x4 pk;
#pragma unroll
    for (int reg = 0; reg < 4; ++reg) pk[reg] = (uint16_t)f2bf_rne(acc[cb][reg]);
    *(u16x4*)(tile + col * 16 + quad * 4) = pk;
  }
  __syncthreads();
  const int t = threadIdx.x;
  if (t < 16) { s1g[i0 + t] = ls1[t]; s2g[i0 + t] = ls2[t]; }
  const int jt = i0 >> 5;
  const int qh = (i0 >> 4) & 1;
  const int c  = t >> 4;
  const int mm = t & 15;
#pragma unroll
  for (int qq = 0; qq < 2; ++qq) {
    uint4 v = *(const uint4*)(tile + (c * 16 + mm) * 16 + qq * 8);
    *(uint4*)(HTf + ((((size_t)jt * 16 + c) * 64) + (qh * 2 + qq) * 16 + mm) * 8) = v;
  }
}

// ---------------------------------------------------------------------------
// K2: fused masked-softmax attention + P@H partial.
// grid = (64, split). 512 thr = 8 waves. Block: 128 rows x 256 cols,
// j-slice [jbeg, +jrange), phase = 32 j = one K-step.
// Producer: lane (r=tid&127, cpr=tid>>7): 8 exps -> P[p&1][cpr][r][8].
// Consumer: wave (rg=w>>2, cg=w&3) owns 64x64: 4 P ds_read_b128 +
//   4 B ds_read_b128 from BL (LDS dbuf, staged one phase ahead via
//   global_load_lds w16) + 16 MFMA under setprio(1). One barrier per phase;
//   the barrier's implicit vmcnt(0) drain is the stage fence.
// ---------------------------------------------------------------------------
__global__ __launch_bounds__(512, 4) void k_attn(const u64* __restrict__ M3,
                                                 const uint16_t* __restrict__ HTf,
                                                 const float* __restrict__ s1,
                                                 const float* __restrict__ s2,
                                                 float* __restrict__ pout,
                                                 float* __restrict__ pden,
                                                 int split) {
  __shared__ uint16_t PL[2][4096];   // [cpr 4][row 128][e 8] = 8 KB each
  __shared__ uint16_t BL[2][8192];   // 32 j x 256 col bf16 = 16 KB each
  __shared__ float lss2[1024];       // 1024-j s2 window
  __shared__ float ldsden[512];

  const int tid  = threadIdx.x;
  const int lane = tid & 63;
  const int w    = tid >> 6;
  const int m    = lane & 15;
  const int q    = lane >> 4;
  const int rg   = w >> 2, cg = w & 3;
  const int r    = tid & 127;
  const int cpr  = tid >> 7;
  const int i0   = blockIdx.x * 128;
  const int sp   = blockIdx.y;
  const int jrange = N_NODES / split;
  const int jbeg   = sp * jrange;
  const int jblk   = jbeg >> 5;
  const int nphase = jrange / 32;

  const float s1r = s1[i0 + r];
  float mi = fmaxf(s1r + MI_SHIFT, LRALPHA * (s1r + MI_SHIFT));

  f32x4 acc[4][4];
#pragma unroll
  for (int rt = 0; rt < 4; ++rt)
#pragma unroll
    for (int cb = 0; cb < 4; ++cb) { f32x4 z = {0.f,0.f,0.f,0.f}; acc[rt][cb] = z; }
  float den = 0.f;

  const u64* mrow = M3 + ((size_t)blockIdx.x * 128 + (jbeg >> 6)) * 128 + r;
  u64 mcur = mrow[0];

  // stage macro: phase pp -> BL[buf]; 2 x 1KB per wave, wave-uniform LDS dest
#define STAGE_B(pp, buf) do {                                                  \
    const uint16_t* s_ = HTf + (((size_t)(jblk + (pp))) << 13) + (w << 10) +   \
                         (lane << 3);                                          \
    __builtin_amdgcn_global_load_lds((gas1_u32)(const void*)s_,                \
        (las3_u32)(void*)(&BL[buf][w << 10]), 16, 0, 0);                       \
    __builtin_amdgcn_global_load_lds((gas1_u32)(const void*)(s_ + 512),        \
        (las3_u32)(void*)(&BL[buf][(w << 10) + 512]), 16, 0, 0);               \
  } while (0)

  STAGE_B(0, 0);   // prologue: phase-0 B tile in flight

#pragma unroll 1
  for (int ph = 0; ph < nphase; ph += 2) {
    // re-stage s2 window every 32 phases (once when split>=8)
    if ((ph & 31) == 0) {
      __syncthreads();   // prior window's lss2 readers done
      if (tid < 256) *(f32x4*)(lss2 + tid * 4) =
        *(const f32x4*)(s2 + jbeg + (ph >> 5) * 1024 + tid * 4);
      __syncthreads();
    }
    // mask prefetch for next pair
    u64 mnx = (ph + 2 < nphase) ? mrow[((ph >> 1) + 1) * 128] : 0;
#pragma unroll
    for (int po = 0; po < 2; ++po) {
      const int p = ph + po;
      // ---- P-gen: 8 exps for (row r, j-window cpr*8 within this phase)
      const int pl = p & 31;
      f32x4 sA = *(const f32x4*)(lss2 + pl * 32 + cpr * 8);
      f32x4 sB = *(const f32x4*)(lss2 + pl * 32 + cpr * 8 + 4);
      const uint32_t by = (uint32_t)(mcur >> ((po * 4 + cpr) * 8)) & 0xffu;
      s16x8 P0;
#pragma unroll
      for (int e = 0; e < 4; ++e) {
        float x0 = s1r + sA[e];
        float pv0 = __expf(fmaxf(x0, LRALPHA * x0) - mi);
        pv0 = ((by >> e) & 1u) ? pv0 : 0.f;
        den += pv0; P0[e] = f2bf_fast(pv0);
        float x1 = s1r + sB[e];
        float pv1 = __expf(fmaxf(x1, LRALPHA * x1) - mi);
        pv1 = ((by >> (e + 4)) & 1u) ? pv1 : 0.f;
        den += pv1; P0[4 + e] = f2bf_fast(pv1);
      }
      *(s16x8*)(PL[p & 1] + (cpr * 128 + r) * 8) = P0;
      // barrier: P-tile ready; implicit vmcnt(0) drains stage(p) (all waves)
      __syncthreads();
      // issue next phase's B stage first so its latency hides under compute
      if (p + 1 < nphase) STAGE_B(p + 1, (p + 1) & 1);
      // ---- consume: P and B from LDS, 16 MFMA
      s16x8 Bv[4];
#pragma unroll
      for (int cb = 0; cb < 4; ++cb)
        Bv[cb] = *(const s16x8*)(&BL[p & 1][((cg * 4 + cb) << 9) + (lane << 3)]);
      s16x8 F[4];
#pragma unroll
      for (int rt = 0; rt < 4; ++rt)
        F[rt] = *(const s16x8*)(PL[p & 1] + (q * 128 + rg * 64 + rt * 16 + m) * 8);
      __builtin_amdgcn_s_setprio(1);
#pragma unroll
      for (int rt = 0; rt < 4; ++rt)
#pragma unroll
        for (int cb = 0; cb < 4; ++cb)
          acc[rt][cb] = __builtin_amdgcn_mfma_f32_16x16x32_bf16(F[rt], Bv[cb], acc[rt][cb], 0, 0, 0);
      __builtin_amdgcn_s_setprio(0);
    }
    mcur = mnx;
  }
#undef STAGE_B

  // ---- denominator: 4 c-windows per row merged via LDS
  ldsden[cpr * 128 + r] = den;
  __syncthreads();
  if (tid < 128) {
    float d = ldsden[tid] + ldsden[128 + tid] + ldsden[256 + tid] + ldsden[384 + tid];
    pden[(size_t)sp * N_NODES + i0 + tid] = d;
  }
  // ---- pout: wave (rg,cg) tile 64x64
#pragma unroll
  for (int rt = 0; rt < 4; ++rt)
#pragma unroll
    for (int cb = 0; cb < 4; ++cb)
#pragma unroll
      for (int reg = 0; reg < 4; ++reg) {
        const int row = i0 + rg * 64 + rt * 16 + q * 4 + reg;
        const int col = cg * 64 + cb * 16 + m;
        pout[((size_t)sp * N_NODES + row) * FOUT + col] = acc[rt][cb][reg];
      }
}

// ---------------------------------------------------------------------------
// K3: out = elu( (sum_s pout[s]) / (sum_s pden[s]) ). In-place safe (split=1).
// ---------------------------------------------------------------------------
__global__ __launch_bounds__(256) void k_reduce(const float* __restrict__ pout,
                                                const float* __restrict__ pden,
                                                float* __restrict__ out,
                                                int split) {
  const int gid = blockIdx.x * 256 + threadIdx.x;
  const int i = gid >> 6;
  const int c = (gid & 63) << 2;
  f32x4 sum = {0.f,0.f,0.f,0.f};
  float den = 0.f;
  for (int s = 0; s < split; ++s) {
    sum += *(const f32x4*)(pout + ((size_t)s * N_NODES + i) * FOUT + c);
    den += pden[(size_t)s * N_NODES + i];
  }
  const float inv = 1.0f / den;
  f32x4 r;
#pragma unroll
  for (int e = 0; e < 4; ++e) {
    float v = sum[e] * inv;
    r[e] = v > 0.f ? v : (__expf(v) - 1.0f);
  }
  *(f32x4*)(out + (size_t)i * FOUT + c) = r;
}

// ---------------------------------------------------------------------------
extern "C" void kernel_launch(void* const* d_in, const int* in_sizes, int n_in,
                              void* d_out, int out_size, void* d_ws, size_t ws_size,
                              hipStream_t stream) {
  const float* X   = (const float*)d_in[0];   // [8192][512]
  const int*   adj = (const int*)d_in[1];     // [8192][8192]
  const float* W   = (const float*)d_in[2];   // [512][256]
  const float* a   = (const float*)d_in[3];   // [512]
  float* out = (float*)d_out;                 // [8192][256]

  char* ws = (char*)d_ws;
  uint16_t* HTf  = (uint16_t*)ws;                                   // 4 MB
  uint16_t* WThi = (uint16_t*)(ws + (4u << 20));                    // 256 KB
  uint16_t* WTlo = (uint16_t*)(ws + (4u << 20) + 262144);           // 256 KB
  float*    s1   = (float*)(ws + (4u << 20) + 524288);              // 32 KB
  float*    s2   = s1 + N_NODES;                                    // 32 KB
  float*    pden = s2 + N_NODES;                                    // <=256 KB
  u64*      M3   = (u64*)(ws + (6u << 20));                         // 8 MB
  const size_t pout_off = (size_t)16u << 20;
  const size_t slab = (size_t)N_NODES * FOUT * sizeof(float);       // 8 MB

  int split;
  if      (ws_size >= pout_off + 8 * slab) split = 8;
  else if (ws_size >= pout_off + 4 * slab) split = 4;
  else if (ws_size >= pout_off + 2 * slab) split = 2;
  else                                     split = 1;
  float* pout = (split == 1) ? out : (float*)(ws + pout_off);

  k_prep<<<dim3(512), dim3(256), 0, stream>>>(W, WThi, WTlo);
  k_pre<<<dim3(2560), dim3(256), 0, stream>>>(X, WThi, WTlo, a, adj, HTf, s1, s2, M3);
  k_attn<<<dim3(N_NODES / 128, split), dim3(512), 0, stream>>>(M3, HTf, s1, s2, pout, pden, split);
  k_reduce<<<dim3(N_NODES * FOUT / 4 / 256), dim3(256), 0, stream>>>(pout, pden, out, split);
}

// Round 2
// 465.662 us; speedup vs baseline: 1.0158x; 1.0043x over previous
//
#include <hip/hip_runtime.h>
#include <stdint.h>
#include <stddef.h>

// GAT layer, N=8192, Fin=512, F=256 on gfx950.
// R9 = fuse the adj stream INTO k_attn (drop M3 + k_pre's mask branch):
// each k_attn block owns a disjoint 128x1024 adj slab; per phase each
// producer thread prefetches its 8 adj ints (2x dwordx4) one phase ahead.
// Producer role remapped to (row=tid>>2, Kquad=tid&3) so a wave's adj loads
// cover 16 full 128B lines (4x fewer L1 txns than row-major lane order).
// Also: MFMA operands swapped (mfma(Bv,F)) -> acc transposed -> pout
// epilogue is 16 coalesced f32x4 stores/thread instead of 64 dword stores.
// R8: B-operand LDS dbuf staging via global_load_lds w16 + setprio (kept).

#define N_NODES 8192
#define FIN     512
#define FOUT    256
#define LRALPHA 0.2f
#define MI_SHIFT 16.0f   // >= max s2 (sigma~1.3); exact-math upper bound

typedef float f32x4 __attribute__((ext_vector_type(4)));
typedef short s16x8 __attribute__((ext_vector_type(8)));
typedef unsigned short u16x4 __attribute__((ext_vector_type(4)));
typedef int   i32x4 __attribute__((ext_vector_type(4)));
typedef unsigned long long u64;

typedef const uint32_t __attribute__((address_space(1)))* gas1_u32;
typedef uint32_t __attribute__((address_space(3)))* las3_u32;

__device__ __forceinline__ short f2bf_rne(float f) {
  uint32_t u = __builtin_bit_cast(uint32_t, f);
  u += 0x7fffu + ((u >> 16) & 1u);
  return (short)(u >> 16);
}
__device__ __forceinline__ short f2bf_fast(float f) {   // round-half-up
  uint32_t u = __builtin_bit_cast(uint32_t, f);
  return (short)((u + 0x8000u) >> 16);
}
__device__ __forceinline__ float bf2f(short s) {
  uint32_t u = ((uint32_t)(uint16_t)s) << 16;
  return __builtin_bit_cast(float, u);
}

// ---------------------------------------------------------------------------
// K0: WThi/WTlo[256][512] bf16 hi/lo split of W (transposed).
// ---------------------------------------------------------------------------
__global__ __launch_bounds__(256) void k_prep(const float* __restrict__ W,
                                              uint16_t* __restrict__ WThi,
                                              uint16_t* __restrict__ WTlo) {
  const int idx = blockIdx.x * 256 + threadIdx.x;
  const int n = idx >> 9;
  const int k = idx & 511;
  float v = W[k * FOUT + n];
  short h = f2bf_rne(v);
  WThi[idx] = (uint16_t)h;
  WTlo[idx] = (uint16_t)f2bf_rne(v - bf2f(h));
}

// ---------------------------------------------------------------------------
// K1: GEMM only (H=X@W + s1/s2 + HTf store). 512 blocks x 16 rows.
// ---------------------------------------------------------------------------
__global__ __launch_bounds__(256, 4) void k_pre(const float* __restrict__ X,
                                                const uint16_t* __restrict__ WThi,
                                                const uint16_t* __restrict__ WTlo,
                                                const float* __restrict__ a,
                                                uint16_t* __restrict__ HTf,
                                                float* __restrict__ s1g,
                                                float* __restrict__ s2g) {
  __shared__ float ls1[16], ls2[16];
  __shared__ uint16_t tile[FOUT * 16];   // [col][row_local]
  const int lane = threadIdx.x & 63;
  const int w    = threadIdx.x >> 6;

  const int m    = lane & 15;
  const int quad = lane >> 4;
  const int i0   = blockIdx.x * 16;
  const int colg = w * 64;

  f32x4 acc[4];
#pragma unroll
  for (int cb = 0; cb < 4; ++cb) { f32x4 z = {0.f,0.f,0.f,0.f}; acc[cb] = z; }

  for (int kt = 0; kt < FIN / 32; ++kt) {
    const int k0 = kt * 32 + quad * 8;
    const float* ap = X + (size_t)(i0 + m) * FIN + k0;
    f32x4 a0 = *(const f32x4*)ap;
    f32x4 a1 = *(const f32x4*)(ap + 4);
    s16x8 ahi, alo;
#pragma unroll
    for (int e = 0; e < 4; ++e) {
      short h0 = f2bf_rne(a0[e]); ahi[e] = h0; alo[e] = f2bf_rne(a0[e] - bf2f(h0));
      short h1 = f2bf_rne(a1[e]); ahi[4+e] = h1; alo[4+e] = f2bf_rne(a1[e] - bf2f(h1));
    }
#pragma unroll
    for (int cb = 0; cb < 4; ++cb) {
      const int n = colg + cb * 16 + m;
      s16x8 bhi = *(const s16x8*)(WThi + (size_t)n * FIN + k0);
      s16x8 blo = *(const s16x8*)(WTlo + (size_t)n * FIN + k0);
      acc[cb] = __builtin_amdgcn_mfma_f32_16x16x32_bf16(ahi, bhi, acc[cb], 0, 0, 0);
      acc[cb] = __builtin_amdgcn_mfma_f32_16x16x32_bf16(ahi, blo, acc[cb], 0, 0, 0);
      acc[cb] = __builtin_amdgcn_mfma_f32_16x16x32_bf16(alo, bhi, acc[cb], 0, 0, 0);
    }
  }

  float p1[4] = {0.f,0.f,0.f,0.f}, p2[4] = {0.f,0.f,0.f,0.f};
#pragma unroll
  for (int cb = 0; cb < 4; ++cb) {
    const int n = colg + cb * 16 + m;
    const float a1c = a[n];
    const float a2c = a[FOUT + n];
#pragma unroll
    for (int reg = 0; reg < 4; ++reg) {
      p1[reg] += acc[cb][reg] * a1c;
      p2[reg] += acc[cb][reg] * a2c;
    }
  }
#pragma unroll
  for (int off = 1; off <= 8; off <<= 1)
#pragma unroll
    for (int reg = 0; reg < 4; ++reg) {
      p1[reg] += __shfl_xor(p1[reg], off);
      p2[reg] += __shfl_xor(p2[reg], off);
    }
  if (threadIdx.x < 16) { ls1[threadIdx.x] = 0.f; ls2[threadIdx.x] = 0.f; }
  __syncthreads();
  if (m == 0) {
#pragma unroll
    for (int reg = 0; reg < 4; ++reg) {
      atomicAdd(&ls1[quad * 4 + reg], p1[reg]);
      atomicAdd(&ls2[quad * 4 + reg], p2[reg]);
    }
  }
#pragma unroll
  for (int cb = 0; cb < 4; ++cb) {
    const int col = colg + cb * 16 + m;
    u16x4 pk;
#pragma unroll
    for (int reg = 0; reg < 4; ++reg) pk[reg] = (uint16_t)f2bf_rne(acc[cb][reg]);
    *(u16x4*)(tile + col * 16 + quad * 4) = pk;
  }
  __syncthreads();
  const int t = threadIdx.x;
  if (t < 16) { s1g[i0 + t] = ls1[t]; s2g[i0 + t] = ls2[t]; }
  const int jt = i0 >> 5;
  const int qh = (i0 >> 4) & 1;
  const int c  = t >> 4;
  const int mm = t & 15;
#pragma unroll
  for (int qq = 0; qq < 2; ++qq) {
    uint4 v = *(const uint4*)(tile + (c * 16 + mm) * 16 + qq * 8);
    *(uint4*)(HTf + ((((size_t)jt * 16 + c) * 64) + (qh * 2 + qq) * 16 + mm) * 8) = v;
  }
}

// ---------------------------------------------------------------------------
// K2: fused adj-mask + softmax attention + P@H partial.
// grid = (64, split). 512 thr = 8 waves. Block: 128 rows x 256 cols,
// j-slice [jbeg, +jrange), phase = 32 j = one K-step.
// Producer thread (rr=tid>>2, cw=tid&3): prefetched 8 adj ints (2x dwordx4,
//   issued one phase ahead) -> 8 exps -> PL[p&1][cw][rr][8]. A wave's adj
//   loads cover 16 full 128B lines (lanes 0..3 = one row's full phase line).
// Consumer wave (rg=w>>2, cg=w&3) owns 64x64: 4 P ds_read_b128 + 4 B
//   ds_read_b128 from BL (LDS dbuf via global_load_lds w16, staged one phase
//   ahead) + 16 swapped MFMA (acc transposed: reg = 4 consecutive cols)
//   under setprio(1). One barrier per phase; its vmcnt(0) drain fences the
//   previous stage.
// ---------------------------------------------------------------------------
__global__ __launch_bounds__(512, 4) void k_attn(const uint16_t* __restrict__ HTf,
                                                 const float* __restrict__ s1,
                                                 const float* __restrict__ s2,
                                                 const int* __restrict__ adj,
                                                 float* __restrict__ pout,
                                                 float* __restrict__ pden,
                                                 int split) {
  __shared__ uint16_t PL[2][4096];   // [cw 4][row 128][e 8] = 8 KB each
  __shared__ uint16_t BL[2][8192];   // 32 j x 256 col bf16 = 16 KB each
  __shared__ float lss2[1024];       // 1024-j s2 window
  __shared__ float ldsden[512];

  const int tid  = threadIdx.x;
  const int lane = tid & 63;
  const int w    = tid >> 6;
  const int m    = lane & 15;
  const int q    = lane >> 4;
  const int rg   = w >> 2, cg = w & 3;
  const int rr   = tid >> 2;         // producer row 0..127
  const int cw   = tid & 3;          // producer K-quad (8-j window)
  const int i0   = blockIdx.x * 128;
  const int sp   = blockIdx.y;
  const int jrange = N_NODES / split;
  const int jbeg   = sp * jrange;
  const int jblk   = jbeg >> 5;
  const int nphase = jrange / 32;

  const float s1r = s1[i0 + rr];
  float mi = fmaxf(s1r + MI_SHIFT, LRALPHA * (s1r + MI_SHIFT));

  f32x4 acc[4][4];
#pragma unroll
  for (int rt = 0; rt < 4; ++rt)
#pragma unroll
    for (int cb = 0; cb < 4; ++cb) { f32x4 z = {0.f,0.f,0.f,0.f}; acc[rt][cb] = z; }
  float den = 0.f;

  // adj slab pointer for this producer thread: 8 ints per phase
  const int* adjp = adj + (size_t)(i0 + rr) * N_NODES + jbeg + cw * 8;
  i32x4 A0 = *(const i32x4*)adjp;          // phase 0 (synchronous)
  i32x4 A1 = *(const i32x4*)(adjp + 4);

  // stage macro: phase pp -> BL[buf]; 2 x 1KB per wave, wave-uniform LDS dest
#define STAGE_B(pp, buf) do {                                                  \
    const uint16_t* s_ = HTf + (((size_t)(jblk + (pp))) << 13) + (w << 10) +   \
                         (lane << 3);                                          \
    __builtin_amdgcn_global_load_lds((gas1_u32)(const void*)s_,                \
        (las3_u32)(void*)(&BL[buf][w << 10]), 16, 0, 0);                       \
    __builtin_amdgcn_global_load_lds((gas1_u32)(const void*)(s_ + 512),        \
        (las3_u32)(void*)(&BL[buf][(w << 10) + 512]), 16, 0, 0);               \
  } while (0)

  STAGE_B(0, 0);   // prologue: phase-0 B tile in flight

#pragma unroll 1
  for (int p = 0; p < nphase; ++p) {
    // re-stage s2 window every 32 phases (once when split>=8)
    if ((p & 31) == 0) {
      __syncthreads();   // prior window's lss2 readers done
      if (tid < 256) *(f32x4*)(lss2 + tid * 4) =
        *(const f32x4*)(s2 + jbeg + (p >> 5) * 1024 + tid * 4);
      __syncthreads();
    }
    // ---- P-gen: 8 exps for (row rr, j-window cw*8 within this phase)
    const int pl = p & 31;
    f32x4 sA = *(const f32x4*)(lss2 + pl * 32 + cw * 8);
    f32x4 sB = *(const f32x4*)(lss2 + pl * 32 + cw * 8 + 4);
    s16x8 P0;
#pragma unroll
    for (int e = 0; e < 4; ++e) {
      float x0 = s1r + sA[e];
      float pv0 = __expf(fmaxf(x0, LRALPHA * x0) - mi);
      pv0 = A0[e] ? pv0 : 0.f;
      den += pv0; P0[e] = f2bf_fast(pv0);
      float x1 = s1r + sB[e];
      float pv1 = __expf(fmaxf(x1, LRALPHA * x1) - mi);
      pv1 = A1[e] ? pv1 : 0.f;
      den += pv1; P0[4 + e] = f2bf_fast(pv1);
    }
    *(s16x8*)(PL[p & 1] + (cw * 128 + rr) * 8) = P0;
    // barrier: P-tile ready; implicit vmcnt(0) drains stage(p) (all waves)
    __syncthreads();
    // issue next phase's adj prefetch + B stage first (latency hides under
    // this phase's MFMA + next phase's exps)
    i32x4 A0n = {0,0,0,0}, A1n = {0,0,0,0};
    if (p + 1 < nphase) {
      const int* np = adjp + (size_t)(p + 1) * 32;
      A0n = *(const i32x4*)np;
      A1n = *(const i32x4*)(np + 4);
      STAGE_B(p + 1, (p + 1) & 1);
    }
    // ---- consume: P and B from LDS, 16 MFMA (swapped operands -> acc^T)
    s16x8 Bv[4];
#pragma unroll
    for (int cb = 0; cb < 4; ++cb)
      Bv[cb] = *(const s16x8*)(&BL[p & 1][((cg * 4 + cb) << 9) + (lane << 3)]);
    s16x8 F[4];
#pragma unroll
    for (int rt = 0; rt < 4; ++rt)
      F[rt] = *(const s16x8*)(PL[p & 1] + (q * 128 + rg * 64 + rt * 16 + m) * 8);
    __builtin_amdgcn_s_setprio(1);
#pragma unroll
    for (int rt = 0; rt < 4; ++rt)
#pragma unroll
      for (int cb = 0; cb < 4; ++cb)
        acc[rt][cb] = __builtin_amdgcn_mfma_f32_16x16x32_bf16(Bv[cb], F[rt], acc[rt][cb], 0, 0, 0);
    __builtin_amdgcn_s_setprio(0);
    A0 = A0n; A1 = A1n;
  }
#undef STAGE_B

  // ---- denominator: 4 j-windows per row merged via LDS
  ldsden[cw * 128 + rr] = den;
  __syncthreads();
  if (tid < 128) {
    float d = ldsden[tid] + ldsden[128 + tid] + ldsden[256 + tid] + ldsden[384 + tid];
    pden[(size_t)sp * N_NODES + i0 + tid] = d;
  }
  // ---- pout: acc is transposed (rows = H-cols): reg = 4 consecutive cols
  // thread element: row = rg*64+rt*16+m (P-row), col = cg*64+cb*16+q*4+reg
#pragma unroll
  for (int rt = 0; rt < 4; ++rt)
#pragma unroll
    for (int cb = 0; cb < 4; ++cb) {
      const int row = i0 + rg * 64 + rt * 16 + m;
      const int col = cg * 64 + cb * 16 + q * 4;
      *(f32x4*)(pout + ((size_t)sp * N_NODES + row) * FOUT + col) = acc[rt][cb];
    }
}

// ---------------------------------------------------------------------------
// K3: out = elu( (sum_s pout[s]) / (sum_s pden[s]) ). In-place safe (split=1).
// ---------------------------------------------------------------------------
__global__ __launch_bounds__(256) void k_reduce(const float* __restrict__ pout,
                                                const float* __restrict__ pden,
                                                float* __restrict__ out,
                                                int split) {
  const int gid = blockIdx.x * 256 + threadIdx.x;
  const int i = gid >> 6;
  const int c = (gid & 63) << 2;
  f32x4 sum = {0.f,0.f,0.f,0.f};
  float den = 0.f;
  for (int s = 0; s < split; ++s) {
    sum += *(const f32x4*)(pout + ((size_t)s * N_NODES + i) * FOUT + c);
    den += pden[(size_t)s * N_NODES + i];
  }
  const float inv = 1.0f / den;
  f32x4 r;
#pragma unroll
  for (int e = 0; e < 4; ++e) {
    float v = sum[e] * inv;
    r[e] = v > 0.f ? v : (__expf(v) - 1.0f);
  }
  *(f32x4*)(out + (size_t)i * FOUT + c) = r;
}

// ---------------------------------------------------------------------------
extern "C" void kernel_launch(void* const* d_in, const int* in_sizes, int n_in,
                              void* d_out, int out_size, void* d_ws, size_t ws_size,
                              hipStream_t stream) {
  const float* X   = (const float*)d_in[0];   // [8192][512]
  const int*   adj = (const int*)d_in[1];     // [8192][8192]
  const float* W   = (const float*)d_in[2];   // [512][256]
  const float* a   = (const float*)d_in[3];   // [512]
  float* out = (float*)d_out;                 // [8192][256]

  char* ws = (char*)d_ws;
  uint16_t* HTf  = (uint16_t*)ws;                                   // 4 MB
  uint16_t* WThi = (uint16_t*)(ws + (4u << 20));                    // 256 KB
  uint16_t* WTlo = (uint16_t*)(ws + (4u << 20) + 262144);           // 256 KB
  float*    s1   = (float*)(ws + (4u << 20) + 524288);              // 32 KB
  float*    s2   = s1 + N_NODES;                                    // 32 KB
  float*    pden = s2 + N_NODES;                                    // <=256 KB
  const size_t pout_off = (size_t)16u << 20;
  const size_t slab = (size_t)N_NODES * FOUT * sizeof(float);       // 8 MB

  int split;
  if      (ws_size >= pout_off + 8 * slab) split = 8;
  else if (ws_size >= pout_off + 4 * slab) split = 4;
  else if (ws_size >= pout_off + 2 * slab) split = 2;
  else                                     split = 1;
  float* pout = (split == 1) ? out : (float*)(ws + pout_off);

  k_prep<<<dim3(512), dim3(256), 0, stream>>>(W, WThi, WTlo);
  k_pre<<<dim3(512), dim3(256), 0, stream>>>(X, WThi, WTlo, a, HTf, s1, s2);
  k_attn<<<dim3(N_NODES / 128, split), dim3(512), 0, stream>>>(HTf, s1, s2, adj, pout, pden, split);
  k_reduce<<<dim3(N_NODES * FOUT / 4 / 256), dim3(256), 0, stream>>>(pout, pden, out, split);
}

// Round 3
// 465.050 us; speedup vs baseline: 1.0171x; 1.0013x over previous
//
#include <hip/hip_runtime.h>
#include <stdint.h>
#include <stddef.h>

// GAT layer, N=8192, Fin=512, F=256 on gfx950.
// R10 = R9 + 2-phase-deep adj register prefetch in k_attn: adj(p+2) issued
// right after barrier(p) -> force-completed by barrier(p+1)'s implicit
// vmcnt(0) drain -> consumed at P-gen(p+2) with ~600cyc in-flight window
// (R9 gave only the MFMA cluster ~200cyc -> ~500cyc P-gen stall/phase).
// VGPR paid for by streaming Bv per-cb in the MFMA loop (liveness 16->4).
// R9: adj fused into k_attn (read once, no M3), swapped-operand MFMA
// (acc^T -> coalesced f32x4 pout stores), B via LDS dbuf global_load_lds.

#define N_NODES 8192
#define FIN     512
#define FOUT    256
#define LRALPHA 0.2f
#define MI_SHIFT 16.0f   // >= max s2 (sigma~1.3); exact-math upper bound

typedef float f32x4 __attribute__((ext_vector_type(4)));
typedef short s16x8 __attribute__((ext_vector_type(8)));
typedef unsigned short u16x4 __attribute__((ext_vector_type(4)));
typedef int   i32x4 __attribute__((ext_vector_type(4)));
typedef unsigned long long u64;

typedef const uint32_t __attribute__((address_space(1)))* gas1_u32;
typedef uint32_t __attribute__((address_space(3)))* las3_u32;

__device__ __forceinline__ short f2bf_rne(float f) {
  uint32_t u = __builtin_bit_cast(uint32_t, f);
  u += 0x7fffu + ((u >> 16) & 1u);
  return (short)(u >> 16);
}
__device__ __forceinline__ short f2bf_fast(float f) {   // round-half-up
  uint32_t u = __builtin_bit_cast(uint32_t, f);
  return (short)((u + 0x8000u) >> 16);
}
__device__ __forceinline__ float bf2f(short s) {
  uint32_t u = ((uint32_t)(uint16_t)s) << 16;
  return __builtin_bit_cast(float, u);
}

// ---------------------------------------------------------------------------
// K0: WThi/WTlo[256][512] bf16 hi/lo split of W (transposed).
// ---------------------------------------------------------------------------
__global__ __launch_bounds__(256) void k_prep(const float* __restrict__ W,
                                              uint16_t* __restrict__ WThi,
                                              uint16_t* __restrict__ WTlo) {
  const int idx = blockIdx.x * 256 + threadIdx.x;
  const int n = idx >> 9;
  const int k = idx & 511;
  float v = W[k * FOUT + n];
  short h = f2bf_rne(v);
  WThi[idx] = (uint16_t)h;
  WTlo[idx] = (uint16_t)f2bf_rne(v - bf2f(h));
}

// ---------------------------------------------------------------------------
// K1: GEMM only (H=X@W + s1/s2 + HTf store). 512 blocks x 16 rows.
// ---------------------------------------------------------------------------
__global__ __launch_bounds__(256, 4) void k_pre(const float* __restrict__ X,
                                                const uint16_t* __restrict__ WThi,
                                                const uint16_t* __restrict__ WTlo,
                                                const float* __restrict__ a,
                                                uint16_t* __restrict__ HTf,
                                                float* __restrict__ s1g,
                                                float* __restrict__ s2g) {
  __shared__ float ls1[16], ls2[16];
  __shared__ uint16_t tile[FOUT * 16];   // [col][row_local]
  const int lane = threadIdx.x & 63;
  const int w    = threadIdx.x >> 6;

  const int m    = lane & 15;
  const int quad = lane >> 4;
  const int i0   = blockIdx.x * 16;
  const int colg = w * 64;

  f32x4 acc[4];
#pragma unroll
  for (int cb = 0; cb < 4; ++cb) { f32x4 z = {0.f,0.f,0.f,0.f}; acc[cb] = z; }

  for (int kt = 0; kt < FIN / 32; ++kt) {
    const int k0 = kt * 32 + quad * 8;
    const float* ap = X + (size_t)(i0 + m) * FIN + k0;
    f32x4 a0 = *(const f32x4*)ap;
    f32x4 a1 = *(const f32x4*)(ap + 4);
    s16x8 ahi, alo;
#pragma unroll
    for (int e = 0; e < 4; ++e) {
      short h0 = f2bf_rne(a0[e]); ahi[e] = h0; alo[e] = f2bf_rne(a0[e] - bf2f(h0));
      short h1 = f2bf_rne(a1[e]); ahi[4+e] = h1; alo[4+e] = f2bf_rne(a1[e] - bf2f(h1));
    }
#pragma unroll
    for (int cb = 0; cb < 4; ++cb) {
      const int n = colg + cb * 16 + m;
      s16x8 bhi = *(const s16x8*)(WThi + (size_t)n * FIN + k0);
      s16x8 blo = *(const s16x8*)(WTlo + (size_t)n * FIN + k0);
      acc[cb] = __builtin_amdgcn_mfma_f32_16x16x32_bf16(ahi, bhi, acc[cb], 0, 0, 0);
      acc[cb] = __builtin_amdgcn_mfma_f32_16x16x32_bf16(ahi, blo, acc[cb], 0, 0, 0);
      acc[cb] = __builtin_amdgcn_mfma_f32_16x16x32_bf16(alo, bhi, acc[cb], 0, 0, 0);
    }
  }

  float p1[4] = {0.f,0.f,0.f,0.f}, p2[4] = {0.f,0.f,0.f,0.f};
#pragma unroll
  for (int cb = 0; cb < 4; ++cb) {
    const int n = colg + cb * 16 + m;
    const float a1c = a[n];
    const float a2c = a[FOUT + n];
#pragma unroll
    for (int reg = 0; reg < 4; ++reg) {
      p1[reg] += acc[cb][reg] * a1c;
      p2[reg] += acc[cb][reg] * a2c;
    }
  }
#pragma unroll
  for (int off = 1; off <= 8; off <<= 1)
#pragma unroll
    for (int reg = 0; reg < 4; ++reg) {
      p1[reg] += __shfl_xor(p1[reg], off);
      p2[reg] += __shfl_xor(p2[reg], off);
    }
  if (threadIdx.x < 16) { ls1[threadIdx.x] = 0.f; ls2[threadIdx.x] = 0.f; }
  __syncthreads();
  if (m == 0) {
#pragma unroll
    for (int reg = 0; reg < 4; ++reg) {
      atomicAdd(&ls1[quad * 4 + reg], p1[reg]);
      atomicAdd(&ls2[quad * 4 + reg], p2[reg]);
    }
  }
#pragma unroll
  for (int cb = 0; cb < 4; ++cb) {
    const int col = colg + cb * 16 + m;
    u16x4 pk;
#pragma unroll
    for (int reg = 0; reg < 4; ++reg) pk[reg] = (uint16_t)f2bf_rne(acc[cb][reg]);
    *(u16x4*)(tile + col * 16 + quad * 4) = pk;
  }
  __syncthreads();
  const int t = threadIdx.x;
  if (t < 16) { s1g[i0 + t] = ls1[t]; s2g[i0 + t] = ls2[t]; }
  const int jt = i0 >> 5;
  const int qh = (i0 >> 4) & 1;
  const int c  = t >> 4;
  const int mm = t & 15;
#pragma unroll
  for (int qq = 0; qq < 2; ++qq) {
    uint4 v = *(const uint4*)(tile + (c * 16 + mm) * 16 + qq * 8);
    *(uint4*)(HTf + ((((size_t)jt * 16 + c) * 64) + (qh * 2 + qq) * 16 + mm) * 8) = v;
  }
}

// ---------------------------------------------------------------------------
// K2: fused adj-mask + softmax attention + P@H partial.
// grid = (64, split). 512 thr = 8 waves. Block: 128 rows x 256 cols,
// j-slice [jbeg, +jrange), phase = 32 j = one K-step.
// Producer thread (rr=tid>>2, cw=tid&3): 2-deep prefetched 8 adj ints
//   (A0=adj(p) consumed, A1=adj(p+1) done-by-barrier(p), A2=adj(p+2) issued
//   post-barrier(p)) -> 8 exps -> PL[p&1][cw][rr][8].
// Consumer wave (rg=w>>2, cg=w&3) owns 64x64: 4 P ds_read_b128 + Bv
//   streamed per-cb from BL (LDS dbuf via global_load_lds w16, staged one
//   phase ahead) + 16 swapped MFMA (acc^T) under setprio(1). One barrier
//   per phase; its vmcnt(0) drain is the stage/prefetch fence.
// ---------------------------------------------------------------------------
__global__ __launch_bounds__(512, 4) void k_attn(const uint16_t* __restrict__ HTf,
                                                 const float* __restrict__ s1,
                                                 const float* __restrict__ s2,
                                                 const int* __restrict__ adj,
                                                 float* __restrict__ pout,
                                                 float* __restrict__ pden,
                                                 int split) {
  __shared__ uint16_t PL[2][4096];   // [cw 4][row 128][e 8] = 8 KB each
  __shared__ uint16_t BL[2][8192];   // 32 j x 256 col bf16 = 16 KB each
  __shared__ float lss2[1024];       // 1024-j s2 window
  __shared__ float ldsden[512];

  const int tid  = threadIdx.x;
  const int lane = tid & 63;
  const int w    = tid >> 6;
  const int m    = lane & 15;
  const int q    = lane >> 4;
  const int rg   = w >> 2, cg = w & 3;
  const int rr   = tid >> 2;         // producer row 0..127
  const int cw   = tid & 3;          // producer K-quad (8-j window)
  const int i0   = blockIdx.x * 128;
  const int sp   = blockIdx.y;
  const int jrange = N_NODES / split;
  const int jbeg   = sp * jrange;
  const int jblk   = jbeg >> 5;
  const int nphase = jrange / 32;

  const float s1r = s1[i0 + rr];
  float mi = fmaxf(s1r + MI_SHIFT, LRALPHA * (s1r + MI_SHIFT));

  f32x4 acc[4][4];
#pragma unroll
  for (int rt = 0; rt < 4; ++rt)
#pragma unroll
    for (int cb = 0; cb < 4; ++cb) { f32x4 z = {0.f,0.f,0.f,0.f}; acc[rt][cb] = z; }
  float den = 0.f;

  // adj slab pointer for this producer thread: 8 ints per phase
  const int* adjp = adj + (size_t)(i0 + rr) * N_NODES + jbeg + cw * 8;
  // 2-deep prefetch pipeline: A0 = adj(p), A1 = adj(p+1) (nphase >= 32)
  i32x4 A0a = *(const i32x4*)adjp;
  i32x4 A0b = *(const i32x4*)(adjp + 4);
  i32x4 A1a = *(const i32x4*)(adjp + 32);
  i32x4 A1b = *(const i32x4*)(adjp + 36);

  // stage macro: phase pp -> BL[buf]; 2 x 1KB per wave, wave-uniform LDS dest
#define STAGE_B(pp, buf) do {                                                  \
    const uint16_t* s_ = HTf + (((size_t)(jblk + (pp))) << 13) + (w << 10) +   \
                         (lane << 3);                                          \
    __builtin_amdgcn_global_load_lds((gas1_u32)(const void*)s_,                \
        (las3_u32)(void*)(&BL[buf][w << 10]), 16, 0, 0);                       \
    __builtin_amdgcn_global_load_lds((gas1_u32)(const void*)(s_ + 512),        \
        (las3_u32)(void*)(&BL[buf][(w << 10) + 512]), 16, 0, 0);               \
  } while (0)

  STAGE_B(0, 0);   // prologue: phase-0 B tile in flight

#pragma unroll 1
  for (int p = 0; p < nphase; ++p) {
    // re-stage s2 window every 32 phases (once when split>=8)
    if ((p & 31) == 0) {
      __syncthreads();   // prior window's lss2 readers done
      if (tid < 256) *(f32x4*)(lss2 + tid * 4) =
        *(const f32x4*)(s2 + jbeg + (p >> 5) * 1024 + tid * 4);
      __syncthreads();
    }
    // ---- P-gen: 8 exps for (row rr, j-window cw*8); consumes A0 which has
    // been complete since barrier(p-1)'s drain -> no vmcnt stall here
    const int pl = p & 31;
    f32x4 sA = *(const f32x4*)(lss2 + pl * 32 + cw * 8);
    f32x4 sB = *(const f32x4*)(lss2 + pl * 32 + cw * 8 + 4);
    s16x8 P0;
#pragma unroll
    for (int e = 0; e < 4; ++e) {
      float x0 = s1r + sA[e];
      float pv0 = __expf(fmaxf(x0, LRALPHA * x0) - mi);
      pv0 = A0a[e] ? pv0 : 0.f;
      den += pv0; P0[e] = f2bf_fast(pv0);
      float x1 = s1r + sB[e];
      float pv1 = __expf(fmaxf(x1, LRALPHA * x1) - mi);
      pv1 = A0b[e] ? pv1 : 0.f;
      den += pv1; P0[4 + e] = f2bf_fast(pv1);
    }
    *(s16x8*)(PL[p & 1] + (cw * 128 + rr) * 8) = P0;
    // barrier: P-tile ready; implicit vmcnt(0) drain completes A1 + BL(p)
    __syncthreads();
    // issue adj(p+2) (2-deep: ~full-phase in-flight window) + B stage(p+1)
    i32x4 A2a = {0,0,0,0}, A2b = {0,0,0,0};
    if (p + 2 < nphase) {
      const int* np = adjp + (size_t)(p + 2) * 32;
      A2a = *(const i32x4*)np;
      A2b = *(const i32x4*)(np + 4);
    }
    if (p + 1 < nphase) STAGE_B(p + 1, (p + 1) & 1);
    // ---- consume: P from LDS, Bv streamed per-cb, 16 MFMA (acc^T)
    s16x8 F[4];
#pragma unroll
    for (int rt = 0; rt < 4; ++rt)
      F[rt] = *(const s16x8*)(PL[p & 1] + (q * 128 + rg * 64 + rt * 16 + m) * 8);
    __builtin_amdgcn_s_setprio(1);
#pragma unroll
    for (int cb = 0; cb < 4; ++cb) {
      s16x8 Bv = *(const s16x8*)(&BL[p & 1][((cg * 4 + cb) << 9) + (lane << 3)]);
#pragma unroll
      for (int rt = 0; rt < 4; ++rt)
        acc[rt][cb] = __builtin_amdgcn_mfma_f32_16x16x32_bf16(Bv, F[rt], acc[rt][cb], 0, 0, 0);
    }
    __builtin_amdgcn_s_setprio(0);
    A0a = A1a; A0b = A1b; A1a = A2a; A1b = A2b;
  }
#undef STAGE_B

  // ---- denominator: 4 j-windows per row merged via LDS
  ldsden[cw * 128 + rr] = den;
  __syncthreads();
  if (tid < 128) {
    float d = ldsden[tid] + ldsden[128 + tid] + ldsden[256 + tid] + ldsden[384 + tid];
    pden[(size_t)sp * N_NODES + i0 + tid] = d;
  }
  // ---- pout: acc is transposed (rows = H-cols): reg = 4 consecutive cols
  // thread element: row = rg*64+rt*16+m (P-row), col = cg*64+cb*16+q*4+reg
#pragma unroll
  for (int rt = 0; rt < 4; ++rt)
#pragma unroll
    for (int cb = 0; cb < 4; ++cb) {
      const int row = i0 + rg * 64 + rt * 16 + m;
      const int col = cg * 64 + cb * 16 + q * 4;
      *(f32x4*)(pout + ((size_t)sp * N_NODES + row) * FOUT + col) = acc[rt][cb];
    }
}

// ---------------------------------------------------------------------------
// K3: out = elu( (sum_s pout[s]) / (sum_s pden[s]) ). In-place safe (split=1).
// ---------------------------------------------------------------------------
__global__ __launch_bounds__(256) void k_reduce(const float* __restrict__ pout,
                                                const float* __restrict__ pden,
                                                float* __restrict__ out,
                                                int split) {
  const int gid = blockIdx.x * 256 + threadIdx.x;
  const int i = gid >> 6;
  const int c = (gid & 63) << 2;
  f32x4 sum = {0.f,0.f,0.f,0.f};
  float den = 0.f;
  for (int s = 0; s < split; ++s) {
    sum += *(const f32x4*)(pout + ((size_t)s * N_NODES + i) * FOUT + c);
    den += pden[(size_t)s * N_NODES + i];
  }
  const float inv = 1.0f / den;
  f32x4 r;
#pragma unroll
  for (int e = 0; e < 4; ++e) {
    float v = sum[e] * inv;
    r[e] = v > 0.f ? v : (__expf(v) - 1.0f);
  }
  *(f32x4*)(out + (size_t)i * FOUT + c) = r;
}

// ---------------------------------------------------------------------------
extern "C" void kernel_launch(void* const* d_in, const int* in_sizes, int n_in,
                              void* d_out, int out_size, void* d_ws, size_t ws_size,
                              hipStream_t stream) {
  const float* X   = (const float*)d_in[0];   // [8192][512]
  const int*   adj = (const int*)d_in[1];     // [8192][8192]
  const float* W   = (const float*)d_in[2];   // [512][256]
  const float* a   = (const float*)d_in[3];   // [512]
  float* out = (float*)d_out;                 // [8192][256]

  char* ws = (char*)d_ws;
  uint16_t* HTf  = (uint16_t*)ws;                                   // 4 MB
  uint16_t* WThi = (uint16_t*)(ws + (4u << 20));                    // 256 KB
  uint16_t* WTlo = (uint16_t*)(ws + (4u << 20) + 262144);           // 256 KB
  float*    s1   = (float*)(ws + (4u << 20) + 524288);              // 32 KB
  float*    s2   = s1 + N_NODES;                                    // 32 KB
  float*    pden = s2 + N_NODES;                                    // <=256 KB
  const size_t pout_off = (size_t)16u << 20;
  const size_t slab = (size_t)N_NODES * FOUT * sizeof(float);       // 8 MB

  int split;
  if      (ws_size >= pout_off + 8 * slab) split = 8;
  else if (ws_size >= pout_off + 4 * slab) split = 4;
  else if (ws_size >= pout_off + 2 * slab) split = 2;
  else                                     split = 1;
  float* pout = (split == 1) ? out : (float*)(ws + pout_off);

  k_prep<<<dim3(512), dim3(256), 0, stream>>>(W, WThi, WTlo);
  k_pre<<<dim3(512), dim3(256), 0, stream>>>(X, WThi, WTlo, a, HTf, s1, s2);
  k_attn<<<dim3(N_NODES / 128, split), dim3(512), 0, stream>>>(HTf, s1, s2, adj, pout, pden, split);
  k_reduce<<<dim3(N_NODES * FOUT / 4 / 256), dim3(256), 0, stream>>>(pout, pden, out, split);
}

// Round 4
// 458.663 us; speedup vs baseline: 1.0313x; 1.0139x over previous
//
#include <hip/hip_runtime.h>
#include <stdint.h>
#include <stddef.h>

// GAT layer, N=8192, Fin=512, F=256 on gfx950.
// R11 = R10 with 64-row blocks / split=4 (was 128-row / split=8): halves the
// pout round-trip (134 -> 67 MB HBM) while keeping 512 blocks (2/CU).
// B-operand L2 re-read grows to 537 MB (~11 TB/s, safe vs 34.5 ceiling).
// Wave tile 32x64 (acc 2x4 f32x4), producer = 4 exps + 1 i32x4 adj/phase,
// den via 8-lane shuffle (LDS pass dropped).
// R10: 2-deep adj register prefetch. R9: adj fused into k_attn (read once),
// swapped-operand MFMA (acc^T -> coalesced f32x4 pout stores). R8: B via
// LDS dbuf global_load_lds w16 + setprio around MFMA cluster.

#define N_NODES 8192
#define FIN     512
#define FOUT    256
#define LRALPHA 0.2f
#define MI_SHIFT 16.0f   // >= max s2 (sigma~1.3); exact-math upper bound

typedef float f32x4 __attribute__((ext_vector_type(4)));
typedef short s16x8 __attribute__((ext_vector_type(8)));
typedef unsigned short u16x4 __attribute__((ext_vector_type(4)));
typedef int   i32x4 __attribute__((ext_vector_type(4)));
typedef unsigned long long u64;

typedef const uint32_t __attribute__((address_space(1)))* gas1_u32;
typedef uint32_t __attribute__((address_space(3)))* las3_u32;

__device__ __forceinline__ short f2bf_rne(float f) {
  uint32_t u = __builtin_bit_cast(uint32_t, f);
  u += 0x7fffu + ((u >> 16) & 1u);
  return (short)(u >> 16);
}
__device__ __forceinline__ short f2bf_fast(float f) {   // round-half-up
  uint32_t u = __builtin_bit_cast(uint32_t, f);
  return (short)((u + 0x8000u) >> 16);
}
__device__ __forceinline__ float bf2f(short s) {
  uint32_t u = ((uint32_t)(uint16_t)s) << 16;
  return __builtin_bit_cast(float, u);
}

// ---------------------------------------------------------------------------
// K0: WThi/WTlo[256][512] bf16 hi/lo split of W (transposed).
// ---------------------------------------------------------------------------
__global__ __launch_bounds__(256) void k_prep(const float* __restrict__ W,
                                              uint16_t* __restrict__ WThi,
                                              uint16_t* __restrict__ WTlo) {
  const int idx = blockIdx.x * 256 + threadIdx.x;
  const int n = idx >> 9;
  const int k = idx & 511;
  float v = W[k * FOUT + n];
  short h = f2bf_rne(v);
  WThi[idx] = (uint16_t)h;
  WTlo[idx] = (uint16_t)f2bf_rne(v - bf2f(h));
}

// ---------------------------------------------------------------------------
// K1: GEMM only (H=X@W + s1/s2 + HTf store). 512 blocks x 16 rows.
// ---------------------------------------------------------------------------
__global__ __launch_bounds__(256, 4) void k_pre(const float* __restrict__ X,
                                                const uint16_t* __restrict__ WThi,
                                                const uint16_t* __restrict__ WTlo,
                                                const float* __restrict__ a,
                                                uint16_t* __restrict__ HTf,
                                                float* __restrict__ s1g,
                                                float* __restrict__ s2g) {
  __shared__ float ls1[16], ls2[16];
  __shared__ uint16_t tile[FOUT * 16];   // [col][row_local]
  const int lane = threadIdx.x & 63;
  const int w    = threadIdx.x >> 6;

  const int m    = lane & 15;
  const int quad = lane >> 4;
  const int i0   = blockIdx.x * 16;
  const int colg = w * 64;

  f32x4 acc[4];
#pragma unroll
  for (int cb = 0; cb < 4; ++cb) { f32x4 z = {0.f,0.f,0.f,0.f}; acc[cb] = z; }

  for (int kt = 0; kt < FIN / 32; ++kt) {
    const int k0 = kt * 32 + quad * 8;
    const float* ap = X + (size_t)(i0 + m) * FIN + k0;
    f32x4 a0 = *(const f32x4*)ap;
    f32x4 a1 = *(const f32x4*)(ap + 4);
    s16x8 ahi, alo;
#pragma unroll
    for (int e = 0; e < 4; ++e) {
      short h0 = f2bf_rne(a0[e]); ahi[e] = h0; alo[e] = f2bf_rne(a0[e] - bf2f(h0));
      short h1 = f2bf_rne(a1[e]); ahi[4+e] = h1; alo[4+e] = f2bf_rne(a1[e] - bf2f(h1));
    }
#pragma unroll
    for (int cb = 0; cb < 4; ++cb) {
      const int n = colg + cb * 16 + m;
      s16x8 bhi = *(const s16x8*)(WThi + (size_t)n * FIN + k0);
      s16x8 blo = *(const s16x8*)(WTlo + (size_t)n * FIN + k0);
      acc[cb] = __builtin_amdgcn_mfma_f32_16x16x32_bf16(ahi, bhi, acc[cb], 0, 0, 0);
      acc[cb] = __builtin_amdgcn_mfma_f32_16x16x32_bf16(ahi, blo, acc[cb], 0, 0, 0);
      acc[cb] = __builtin_amdgcn_mfma_f32_16x16x32_bf16(alo, bhi, acc[cb], 0, 0, 0);
    }
  }

  float p1[4] = {0.f,0.f,0.f,0.f}, p2[4] = {0.f,0.f,0.f,0.f};
#pragma unroll
  for (int cb = 0; cb < 4; ++cb) {
    const int n = colg + cb * 16 + m;
    const float a1c = a[n];
    const float a2c = a[FOUT + n];
#pragma unroll
    for (int reg = 0; reg < 4; ++reg) {
      p1[reg] += acc[cb][reg] * a1c;
      p2[reg] += acc[cb][reg] * a2c;
    }
  }
#pragma unroll
  for (int off = 1; off <= 8; off <<= 1)
#pragma unroll
    for (int reg = 0; reg < 4; ++reg) {
      p1[reg] += __shfl_xor(p1[reg], off);
      p2[reg] += __shfl_xor(p2[reg], off);
    }
  if (threadIdx.x < 16) { ls1[threadIdx.x] = 0.f; ls2[threadIdx.x] = 0.f; }
  __syncthreads();
  if (m == 0) {
#pragma unroll
    for (int reg = 0; reg < 4; ++reg) {
      atomicAdd(&ls1[quad * 4 + reg], p1[reg]);
      atomicAdd(&ls2[quad * 4 + reg], p2[reg]);
    }
  }
#pragma unroll
  for (int cb = 0; cb < 4; ++cb) {
    const int col = colg + cb * 16 + m;
    u16x4 pk;
#pragma unroll
    for (int reg = 0; reg < 4; ++reg) pk[reg] = (uint16_t)f2bf_rne(acc[cb][reg]);
    *(u16x4*)(tile + col * 16 + quad * 4) = pk;
  }
  __syncthreads();
  const int t = threadIdx.x;
  if (t < 16) { s1g[i0 + t] = ls1[t]; s2g[i0 + t] = ls2[t]; }
  const int jt = i0 >> 5;
  const int qh = (i0 >> 4) & 1;
  const int c  = t >> 4;
  const int mm = t & 15;
#pragma unroll
  for (int qq = 0; qq < 2; ++qq) {
    uint4 v = *(const uint4*)(tile + (c * 16 + mm) * 16 + qq * 8);
    *(uint4*)(HTf + ((((size_t)jt * 16 + c) * 64) + (qh * 2 + qq) * 16 + mm) * 8) = v;
  }
}

// ---------------------------------------------------------------------------
// K2: fused adj-mask + softmax attention + P@H partial.
// grid = (128, split). 512 thr = 8 waves. Block: 64 rows x 256 cols,
// j-slice [jbeg, +jrange), phase = 32 j = one K-step.
// Producer thread (rr=tid>>3, cw=tid&7): 2-deep prefetched 4 adj ints
//   (A0=adj(p) consumed, A1=adj(p+1) done-by-barrier(p), A2=adj(p+2) issued
//   post-barrier(p)) -> 4 exps -> PL[p&1][cw>>1][rr][(cw&1)*4 .. +4].
// Consumer wave (rg=w>>2, cg=w&3) owns 32x64: 2 F ds_read_b128 + Bv
//   streamed per-cb from BL (LDS dbuf via global_load_lds w16, staged one
//   phase ahead) + 8 swapped MFMA (acc^T) under setprio(1). One barrier per
//   phase; its vmcnt(0) drain is the stage/prefetch fence.
// Den: per-thread over own j's -> 8-lane shuffle reduce -> pden.
// ---------------------------------------------------------------------------
__global__ __launch_bounds__(512, 4) void k_attn(const uint16_t* __restrict__ HTf,
                                                 const float* __restrict__ s1,
                                                 const float* __restrict__ s2,
                                                 const int* __restrict__ adj,
                                                 float* __restrict__ pout,
                                                 float* __restrict__ pden,
                                                 int split) {
  __shared__ uint16_t PL[2][2048];   // [jq 4][row 64][e 8] = 4 KB each
  __shared__ uint16_t BL[2][8192];   // 32 j x 256 col bf16 = 16 KB each
  __shared__ float lss2[1024];       // 1024-j s2 window

  const int tid  = threadIdx.x;
  const int lane = tid & 63;
  const int w    = tid >> 6;
  const int m    = lane & 15;
  const int q    = lane >> 4;
  const int rg   = w >> 2, cg = w & 3;
  const int rr   = tid >> 3;         // producer row 0..63
  const int cw   = tid & 7;          // producer j-quad (4-j window)
  const int i0   = blockIdx.x * 64;
  const int sp   = blockIdx.y;
  const int jrange = N_NODES / split;
  const int jbeg   = sp * jrange;
  const int jblk   = jbeg >> 5;
  const int nphase = jrange / 32;

  const float s1r = s1[i0 + rr];
  float mi = fmaxf(s1r + MI_SHIFT, LRALPHA * (s1r + MI_SHIFT));

  f32x4 acc[2][4];
#pragma unroll
  for (int rt = 0; rt < 2; ++rt)
#pragma unroll
    for (int cb = 0; cb < 4; ++cb) { f32x4 z = {0.f,0.f,0.f,0.f}; acc[rt][cb] = z; }
  float den = 0.f;

  // adj slab pointer for this producer thread: 4 ints per phase
  const int* adjp = adj + (size_t)(i0 + rr) * N_NODES + jbeg + cw * 4;
  // 2-deep prefetch pipeline: A0 = adj(p), A1 = adj(p+1) (nphase >= 2)
  i32x4 A0 = *(const i32x4*)adjp;
  i32x4 A1 = *(const i32x4*)(adjp + 32);

  // stage macro: phase pp -> BL[buf]; 2 x 1KB per wave, wave-uniform LDS dest
#define STAGE_B(pp, buf) do {                                                  \
    const uint16_t* s_ = HTf + (((size_t)(jblk + (pp))) << 13) + (w << 10) +   \
                         (lane << 3);                                          \
    __builtin_amdgcn_global_load_lds((gas1_u32)(const void*)s_,                \
        (las3_u32)(void*)(&BL[buf][w << 10]), 16, 0, 0);                       \
    __builtin_amdgcn_global_load_lds((gas1_u32)(const void*)(s_ + 512),        \
        (las3_u32)(void*)(&BL[buf][(w << 10) + 512]), 16, 0, 0);               \
  } while (0)

  STAGE_B(0, 0);   // prologue: phase-0 B tile in flight

#pragma unroll 1
  for (int p = 0; p < nphase; ++p) {
    // re-stage s2 window every 32 phases
    if ((p & 31) == 0) {
      __syncthreads();   // prior window's lss2 readers done
      if (tid < 256) *(f32x4*)(lss2 + tid * 4) =
        *(const f32x4*)(s2 + jbeg + (p >> 5) * 1024 + tid * 4);
      __syncthreads();
    }
    // ---- P-gen: 4 exps for (row rr, j-window cw*4); consumes A0 which has
    // been complete since barrier(p-1)'s drain -> no vmcnt stall here
    const int pl = p & 31;
    f32x4 sA = *(const f32x4*)(lss2 + pl * 32 + cw * 4);
    u16x4 P0;
#pragma unroll
    for (int e = 0; e < 4; ++e) {
      float x0 = s1r + sA[e];
      float pv0 = __expf(fmaxf(x0, LRALPHA * x0) - mi);
      pv0 = A0[e] ? pv0 : 0.f;
      den += pv0; P0[e] = (uint16_t)f2bf_fast(pv0);
    }
    *(u16x4*)(PL[p & 1] + (((cw >> 1) * 64 + rr) * 8) + (cw & 1) * 4) = P0;
    // barrier: P-tile ready; implicit vmcnt(0) drain completes A1 + BL(p)
    __syncthreads();
    // issue adj(p+2) (2-deep: ~full-phase in-flight window) + B stage(p+1)
    i32x4 A2 = {0,0,0,0};
    if (p + 2 < nphase) A2 = *(const i32x4*)(adjp + (size_t)(p + 2) * 32);
    if (p + 1 < nphase) STAGE_B(p + 1, (p + 1) & 1);
    // ---- consume: P from LDS (2 F frags), Bv streamed per-cb, 8 MFMA
    s16x8 F[2];
#pragma unroll
    for (int rt = 0; rt < 2; ++rt)
      F[rt] = *(const s16x8*)(PL[p & 1] + (q * 64 + rg * 32 + rt * 16 + m) * 8);
    __builtin_amdgcn_s_setprio(1);
#pragma unroll
    for (int cb = 0; cb < 4; ++cb) {
      s16x8 Bv = *(const s16x8*)(&BL[p & 1][((cg * 4 + cb) << 9) + (lane << 3)]);
#pragma unroll
      for (int rt = 0; rt < 2; ++rt)
        acc[rt][cb] = __builtin_amdgcn_mfma_f32_16x16x32_bf16(Bv, F[rt], acc[rt][cb], 0, 0, 0);
    }
    __builtin_amdgcn_s_setprio(0);
    A0 = A1; A1 = A2;
  }
#undef STAGE_B

  // ---- denominator: 8 threads per row (cw 0..7, contiguous lanes) -> shuffle
  den += __shfl_xor(den, 1);
  den += __shfl_xor(den, 2);
  den += __shfl_xor(den, 4);
  if (cw == 0) pden[(size_t)sp * N_NODES + i0 + rr] = den;

  // ---- pout: acc is transposed (rows = H-cols): reg = 4 consecutive cols
  // thread element: row = rg*32+rt*16+m (P-row), col = cg*64+cb*16+q*4+reg
#pragma unroll
  for (int rt = 0; rt < 2; ++rt)
#pragma unroll
    for (int cb = 0; cb < 4; ++cb) {
      const int row = i0 + rg * 32 + rt * 16 + m;
      const int col = cg * 64 + cb * 16 + q * 4;
      *(f32x4*)(pout + ((size_t)sp * N_NODES + row) * FOUT + col) = acc[rt][cb];
    }
}

// ---------------------------------------------------------------------------
// K3: out = elu( (sum_s pout[s]) / (sum_s pden[s]) ). In-place safe (split=1).
// ---------------------------------------------------------------------------
__global__ __launch_bounds__(256) void k_reduce(const float* __restrict__ pout,
                                                const float* __restrict__ pden,
                                                float* __restrict__ out,
                                                int split) {
  const int gid = blockIdx.x * 256 + threadIdx.x;
  const int i = gid >> 6;
  const int c = (gid & 63) << 2;
  f32x4 sum = {0.f,0.f,0.f,0.f};
  float den = 0.f;
  for (int s = 0; s < split; ++s) {
    sum += *(const f32x4*)(pout + ((size_t)s * N_NODES + i) * FOUT + c);
    den += pden[(size_t)s * N_NODES + i];
  }
  const float inv = 1.0f / den;
  f32x4 r;
#pragma unroll
  for (int e = 0; e < 4; ++e) {
    float v = sum[e] * inv;
    r[e] = v > 0.f ? v : (__expf(v) - 1.0f);
  }
  *(f32x4*)(out + (size_t)i * FOUT + c) = r;
}

// ---------------------------------------------------------------------------
extern "C" void kernel_launch(void* const* d_in, const int* in_sizes, int n_in,
                              void* d_out, int out_size, void* d_ws, size_t ws_size,
                              hipStream_t stream) {
  const float* X   = (const float*)d_in[0];   // [8192][512]
  const int*   adj = (const int*)d_in[1];     // [8192][8192]
  const float* W   = (const float*)d_in[2];   // [512][256]
  const float* a   = (const float*)d_in[3];   // [512]
  float* out = (float*)d_out;                 // [8192][256]

  char* ws = (char*)d_ws;
  uint16_t* HTf  = (uint16_t*)ws;                                   // 4 MB
  uint16_t* WThi = (uint16_t*)(ws + (4u << 20));                    // 256 KB
  uint16_t* WTlo = (uint16_t*)(ws + (4u << 20) + 262144);           // 256 KB
  float*    s1   = (float*)(ws + (4u << 20) + 524288);              // 32 KB
  float*    s2   = s1 + N_NODES;                                    // 32 KB
  float*    pden = s2 + N_NODES;                                    // <=256 KB
  const size_t pout_off = (size_t)16u << 20;
  const size_t slab = (size_t)N_NODES * FOUT * sizeof(float);       // 8 MB

  int split;
  if      (ws_size >= pout_off + 4 * slab) split = 4;   // 64-row blocks: 4 is enough for 512 blocks
  else if (ws_size >= pout_off + 2 * slab) split = 2;
  else                                     split = 1;
  float* pout = (split == 1) ? out : (float*)(ws + pout_off);

  k_prep<<<dim3(512), dim3(256), 0, stream>>>(W, WThi, WTlo);
  k_pre<<<dim3(512), dim3(256), 0, stream>>>(X, WThi, WTlo, a, HTf, s1, s2);
  k_attn<<<dim3(N_NODES / 64, split), dim3(512), 0, stream>>>(HTf, s1, s2, adj, pout, pden, split);
  k_reduce<<<dim3(N_NODES * FOUT / 4 / 256), dim3(256), 0, stream>>>(pout, pden, out, split);
}